// Round 1
// baseline (77.094 us; speedup 1.0000x reference)
//
#include <hip/hip_runtime.h>
#include <math.h>

#define IMG_W 112
#define HW    12544          // 112*112
#define CI    8
#define CO    16
#define NP2   36             // patch-position pairs (72 p's / 2)
#define EPS   1e-6f

typedef __attribute__((ext_vector_type(8))) short short8;   // 8 bf16 = 4 VGPRs
typedef __attribute__((ext_vector_type(16))) float f32x16;  // 32x32 MFMA C/D

static __device__ inline short f2bf(float f) {  // RNE float->bf16 bits
  unsigned u = __float_as_uint(f);
  return (short)((u + 0x7FFFu + ((u >> 16) & 1u)) >> 16);
}

static constexpr int DQ[9] = {-113, -112, -111, -1, 0, 1, 111, 112, 113};

// Round 9: switch 16x16x32 -> 32x32x16 MFMA.
//   M=32 rows = p-pair (2 patch positions x 16 C_out), N=32 pixels,
//   K=16: slots 0-7 = input channels, slot 8 = bias (B supplies 1.0), 9-15 = 0.
//   All 64 lanes carry real A rows (lanes 32-63 hold the K=8..15 group) -- no
//   zero-fragment quads, K-util 9/16 instead of 9/32. MFMA count drops 4x
//   (56,448 vs 225,792) and A-fragment LDS reads per pixel drop 4x.
//   C/D layout (m74/m101): col = lane&31 (pixel), row = (i&3)+8*(i>>2)+4*hi,
//   so lane i-reg -> p_local = i>>3, acc slot = i&7 (8 C_out per lane-half):
//   the per-p patch weighting folds in as acc[i&7] += pv[i>>3]*d[i], and the
//   epilogue stores are direct per-lane (no transpose).
// Geometry: 784 blocks x 256 threads; wave = (p-half hh, pixel-group g):
//   g owns 32 consecutive pixels, hh owns p-pairs [hh*18, hh*18+18).
//   784 blocks @ 46KB LDS = 3 blocks/CU resident (768 slots) -> 1.06 rounds.
//   Halves combine acc/n2 via LDS (halo buffer is dead by then), hh=0 stores.
__global__ __launch_bounds__(256, 3) void coda_mfma(
    const float* __restrict__ in, const float* __restrict__ wp,
    const float* __restrict__ bp, float* __restrict__ out)
{
  __shared__ short sA[NP2][2][32][8];  // 36864B: [p-pair][K-group][row m][8 bf16]
  __shared__ float sBuf[CI * 290];     //  9280B: input halo, then 2048-f partials

  const int tid = threadIdx.x;
  const int b   = blockIdx.x / 196;            // 196 blocks (64 px) per image
  const int r0  = (blockIdx.x - b * 196) * 64; // first flat pixel of block
  const float* __restrict__ inb = in + b * CI * HW;

  // ---- stage A-fragments: row o' = p2*32 + m = p*16 + co ----
  for (int idx = tid; idx < NP2 * 64; idx += 256) {
    const int p2 = idx >> 6, l = idx & 63, ah = l >> 5, m = l & 31;
    const int row = p2 * 32 + m;
    short8 v = {0, 0, 0, 0, 0, 0, 0, 0};
    if (ah == 0) {                               // K 0..7: the 8 channel weights
      const float* wr = wp + row * CI;
#pragma unroll
      for (int j = 0; j < 8; ++j) v[j] = f2bf(wr[j]);
    } else {                                     // K 8..15: bias at K=8
      v[0] = f2bf(bp[row]);
    }
    *(short8*)&sA[p2][ah][m][0] = v;
  }
  // ---- stage input halo: flat offsets [r0-113, r0+176] clamped ----
  for (int k = tid; k < CI * 290; k += 256) {
    const int c = k / 290;
    const int i = k - c * 290;
    int gg = r0 - 113 + i;
    gg = (gg < 0) ? 0 : (gg > HW - 1 ? HW - 1 : gg);
    sBuf[k] = inb[c * HW + gg];
  }
  __syncthreads();

  const int wave = tid >> 6;
  const int lane = tid & 63;
  const int g    = wave & 1;                   // pixel group (32 px)
  const int hh   = wave >> 1;                  // p-half: p-pairs [hh*18, hh*18+18)
  const int ln   = lane & 31;                  // pixel slot = D col = A/B row/col
  const int hi   = lane >> 5;                  // K-group for A/B, row-half for D
  const int px   = r0 + g * 32 + ln;
  const int hrow = px / IMG_W;
  const int wcol = px - hrow * IMG_W;
  const int off  = g * 32 + ln + 113;          // center index into sBuf rows

  // border masks per q = kh*3+kw
  float vm[9];
#pragma unroll
  for (int q = 0; q < 9; ++q) {
    const int kh = q / 3, kw = q % 3;
    const bool ok = ((unsigned)(hrow + kh - 1) < 112u) &&
                    ((unsigned)(wcol + kw - 1) < 112u);
    vm[q] = ok ? 1.f : 0.f;
  }

  // B fragment: hi=0 lanes = x[c=0..7, px] bf16; hi=1 lanes = 1.0 at K=8
  short8 bf;
#pragma unroll
  for (int j = 0; j < 8; ++j) {
    const short bv = f2bf(sBuf[j * 290 + off]);
    bf[j] = (hi == 0) ? bv : ((j == 0) ? (short)0x3F80 : (short)0);
  }

  float acc[8] = {0.f, 0.f, 0.f, 0.f, 0.f, 0.f, 0.f, 0.f};
  float n2[8]  = {0.f, 0.f, 0.f, 0.f, 0.f, 0.f, 0.f, 0.f};

#pragma unroll
  for (int t = 0; t < 18; ++t) {
    // p-pair p2 = hh*18 + t; p0 = 36*hh + 2t, p1 = p0+1.
    // 36*hh is divisible by 9, so c/q split is compile-time in t:
    const int c0_ = 4 * hh + (2 * t) / 9;
    const int q0_ = (2 * t) % 9;
    const int c1_ = 4 * hh + (2 * t + 1) / 9;
    const int q1_ = (2 * t + 1) % 9;

    const short8 af = *(const short8*)&sA[hh * 18 + t][hi][ln][0];
    const float pv0 = vm[q0_] * sBuf[c0_ * 290 + off + DQ[q0_]];
    const float pv1 = vm[q1_] * sBuf[c1_ * 290 + off + DQ[q1_]];

    const f32x16 zc = {0.f, 0.f, 0.f, 0.f, 0.f, 0.f, 0.f, 0.f,
                       0.f, 0.f, 0.f, 0.f, 0.f, 0.f, 0.f, 0.f};
    const f32x16 d =
        __builtin_amdgcn_mfma_f32_32x32x16_bf16(af, bf, zc, 0, 0, 0);
#pragma unroll
    for (int i = 0; i < 16; ++i) {             // i>>3 = p_local, i&7 = acc slot
      const float pv = (i < 8) ? pv0 : pv1;
      acc[i & 7] = fmaf(pv, d[i], acc[i & 7]);
      n2[i & 7]  = fmaf(d[i], d[i], n2[i & 7]);
    }
  }

  // ---- combine p-halves via LDS (sBuf halo is dead now), hh=0 stores ----
  __syncthreads();
  if (hh == 1) {
#pragma unroll
    for (int j = 0; j < 8; ++j) {
      sBuf[j * 128 + g * 64 + lane]       = acc[j];   // lane-stride-1: no conflicts
      sBuf[(j + 8) * 128 + g * 64 + lane] = n2[j];
    }
  }
  __syncthreads();
  if (hh == 0) {
    float* __restrict__ ob = out + (long)b * CO * HW + px;
#pragma unroll
    for (int j = 0; j < 8; ++j) {
      const float a2 = acc[j] + sBuf[j * 128 + g * 64 + lane];
      const float s2 = n2[j] + sBuf[(j + 8) * 128 + g * 64 + lane];
      const int co = (j & 3) + 8 * (j >> 2) + 4 * hi;
      ob[(long)co * HW] = a2 / (sqrtf(s2) + EPS);
    }
  }
}

extern "C" void kernel_launch(void* const* d_in, const int* in_sizes, int n_in,
                              void* d_out, int out_size, void* d_ws, size_t ws_size,
                              hipStream_t stream) {
  const float* in = (const float*)d_in[0];
  const float* wp = (const float*)d_in[1];
  const float* bp = (const float*)d_in[2];
  float* out = (float*)d_out;

  // 50176 pixels / 64 per block = 784 blocks of 4 waves (2 px-groups x 2 p-halves)
  coda_mfma<<<dim3(784), dim3(256), 0, stream>>>(in, wp, bp, out);
}

// Round 2
// 72.602 us; speedup vs baseline: 1.0619x; 1.0619x over previous
//
#include <hip/hip_runtime.h>
#include <math.h>

#define IMG_W 112
#define HW    12544          // 112*112
#define CI    8
#define CO    16
#define NP2   36             // patch-position pairs (72 p's / 2)
#define EPS   1e-6f

typedef __attribute__((ext_vector_type(8))) short short8;   // 8 bf16 = 4 VGPRs
typedef __attribute__((ext_vector_type(16))) float f32x16;  // 32x32 MFMA C/D

static __device__ inline short f2bf(float f) {  // RNE float->bf16 bits
  unsigned u = __float_as_uint(f);
  return (short)((u + 0x7FFFu + ((u >> 16) & 1u)) >> 16);
}

static constexpr int DQ[9] = {-113, -112, -111, -1, 0, 1, 111, 112, 113};

// Round 10: remove the per-block critical path.
//   - coda_pack (once): packs A-fragments [p2][lane][8 bf16] into d_ws.
//     Row o' = p2*32 + (lane&31); lane>>5 selects K-group (0..7 = weights,
//     8 = bias, 9..15 = 0). Same lane->fragment mapping the round-9 LDS
//     read used (harness-verified); now one global_load_dwordx4 per MFMA.
//   - main kernel: NO LDS staging, NO f2bf, NO barrier before the loop.
//     Input is 1.6MB (L2-resident) -> pv = 2 coalesced b32 loads/iter with
//     clamp+mask (same semantics as the old halo). LDS = 8KB partials only.
//   - 784 blocks x 256 thr (4 waves = 2 px-groups x 2 p-halves, 18 MFMA/wave),
//     __launch_bounds__(256,4): ~90 VGPR, 8KB LDS -> all 784 blocks
//     co-resident (<=4/CU), single round, one barrier total.
__global__ __launch_bounds__(256) void coda_pack(
    const float* __restrict__ wp, const float* __restrict__ bp,
    short* __restrict__ wpk)
{
  const int t = blockIdx.x * 256 + threadIdx.x;   // 0..2303 = NP2*64
  if (t >= NP2 * 64) return;
  const int p2 = t >> 6, l = t & 63, ah = l >> 5, m = l & 31;
  const int row = p2 * 32 + m;                    // o' = p*16 + co
  short8 v = {0, 0, 0, 0, 0, 0, 0, 0};
  if (ah == 0) {                                  // K 0..7: channel weights
    const float* wr = wp + row * CI;
#pragma unroll
    for (int j = 0; j < 8; ++j) v[j] = f2bf(wr[j]);
  } else {                                        // K 8..15: bias at K=8
    v[0] = f2bf(bp[row]);
  }
  *(short8*)&wpk[t * 8] = v;
}

__global__ __launch_bounds__(256, 4) void coda_mfma(
    const float* __restrict__ in, const short* __restrict__ wpk,
    float* __restrict__ out)
{
  __shared__ float sPart[2 * 16 * 64];            // 8192B: p-half partials

  const int tid = threadIdx.x;
  const int b   = blockIdx.x / 196;               // 196 blocks (64 px) per image
  const int r0  = (blockIdx.x - b * 196) * 64;    // first flat pixel of block
  const float* __restrict__ inb = in + b * CI * HW;

  const int wave = tid >> 6;
  const int lane = tid & 63;
  const int g    = wave & 1;                      // pixel group (32 px)
  const int hh   = wave >> 1;                     // p-half: pairs [hh*18, hh*18+18)
  const int ln   = lane & 31;                     // pixel slot = D col
  const int hi   = lane >> 5;                     // K-group / D row-half
  const int px   = r0 + g * 32 + ln;
  const int hrow = px / IMG_W;
  const int wcol = px - hrow * IMG_W;

  // border masks per q = kh*3+kw
  float vm[9];
#pragma unroll
  for (int q = 0; q < 9; ++q) {
    const int kh = q / 3, kw = q % 3;
    const bool ok = ((unsigned)(hrow + kh - 1) < 112u) &&
                    ((unsigned)(wcol + kw - 1) < 112u);
    vm[q] = ok ? 1.f : 0.f;
  }

  // B fragment: hi=0 lanes = x[c=0..7, px] bf16; hi=1 lanes = 1.0 at K=8
  short8 bf;
#pragma unroll
  for (int j = 0; j < 8; ++j) {
    const short bv = f2bf(inb[j * HW + px]);
    bf[j] = (hi == 0) ? bv : ((j == 0) ? (short)0x3F80 : (short)0);
  }

  float acc[8] = {0.f, 0.f, 0.f, 0.f, 0.f, 0.f, 0.f, 0.f};
  float n2[8]  = {0.f, 0.f, 0.f, 0.f, 0.f, 0.f, 0.f, 0.f};

  // per-lane A-fragment base: ((hh*18 + t)*64 + lane) * 8 shorts
  const short* __restrict__ wbase = wpk + (hh * 18 * 64 + lane) * 8;

#pragma unroll
  for (int t = 0; t < 18; ++t) {
    // pair p2 = hh*18 + t; p0 = 36*hh + 2t, p1 = p0+1 (c/q compile-time in t)
    const int p0  = 36 * hh + 2 * t;
    const int c0_ = p0 / 9,       q0_ = p0 % 9;
    const int c1_ = (p0 + 1) / 9, q1_ = (p0 + 1) % 9;

    const short8 af = *(const short8*)(wbase + t * 512);

    int i0 = px + DQ[q0_]; i0 = i0 < 0 ? 0 : (i0 > HW - 1 ? HW - 1 : i0);
    int i1 = px + DQ[q1_]; i1 = i1 < 0 ? 0 : (i1 > HW - 1 ? HW - 1 : i1);
    const float pv0 = vm[q0_] * inb[c0_ * HW + i0];
    const float pv1 = vm[q1_] * inb[c1_ * HW + i1];

    const f32x16 zc = {0.f, 0.f, 0.f, 0.f, 0.f, 0.f, 0.f, 0.f,
                       0.f, 0.f, 0.f, 0.f, 0.f, 0.f, 0.f, 0.f};
    const f32x16 d =
        __builtin_amdgcn_mfma_f32_32x32x16_bf16(af, bf, zc, 0, 0, 0);
#pragma unroll
    for (int i = 0; i < 16; ++i) {                // i>>3 = p_local, i&7 = slot
      const float pv = (i < 8) ? pv0 : pv1;
      acc[i & 7] = fmaf(pv, d[i], acc[i & 7]);
      n2[i & 7]  = fmaf(d[i], d[i], n2[i & 7]);
    }
  }

  // ---- combine p-halves via LDS, hh=0 stores ----
  if (hh == 1) {
#pragma unroll
    for (int j = 0; j < 8; ++j) {
      sPart[(g * 16 + j) * 64 + lane]     = acc[j];   // lane-stride-1: no conflicts
      sPart[(g * 16 + j + 8) * 64 + lane] = n2[j];
    }
  }
  __syncthreads();
  if (hh == 0) {
    float* __restrict__ ob = out + (long)b * CO * HW + px;
#pragma unroll
    for (int j = 0; j < 8; ++j) {
      const float a2 = acc[j] + sPart[(g * 16 + j) * 64 + lane];
      const float s2 = n2[j] + sPart[(g * 16 + j + 8) * 64 + lane];
      const int co = (j & 3) + 8 * (j >> 2) + 4 * hi;
      ob[(long)co * HW] = a2 / (sqrtf(s2) + EPS);
    }
  }
}

extern "C" void kernel_launch(void* const* d_in, const int* in_sizes, int n_in,
                              void* d_out, int out_size, void* d_ws, size_t ws_size,
                              hipStream_t stream) {
  const float* in = (const float*)d_in[0];
  const float* wp = (const float*)d_in[1];
  const float* bp = (const float*)d_in[2];
  float* out = (float*)d_out;
  short* wpk = (short*)d_ws;                      // 36*64*8 shorts = 36,864 B

  // pack A-fragments once (9 blocks x 256 = 2304 threads = NP2*64)
  coda_pack<<<dim3(9), dim3(256), 0, stream>>>(wp, bp, wpk);
  // 50176 px / 64 per block = 784 blocks of 4 waves (2 px-groups x 2 p-halves)
  coda_mfma<<<dim3(784), dim3(256), 0, stream>>>(in, wpk, out);
}